// Round 7
// baseline (767.762 us; speedup 1.0000x reference)
//
#include <hip/hip_runtime.h>
#include <cstdint>
#include <cstddef>

#define DIM_D 32
#define KIN   66
#define NSTE  100
#define BATCHN 4096
#define ROWS  16
#define BLKT  1024
#define NBLK  (BATCHN / ROWS)   // 256 blocks, 1/CU, 16 waves = 4 waves/SIMD

#define CTRL_OFF 0
#define X_OFF ((size_t)BATCHN * NSTE * DIM_D)
#define J_OFF (X_OFF + (size_t)BATCHN * NSTE * 65)

// bf16 weight arrays in d_ws (element offsets)
#define W1B_OFF 0            // [256][96] (cols 66..95 zero)
#define W2B_OFF 24576        // [256][256]
#define W3B_OFF 90112        // [256][256]
#define W4B_OFF 155648       // [32][256]
#define WS_ELEMS 163840

constexpr float DT_C = 0.01f;

typedef __bf16 bf16x8 __attribute__((ext_vector_type(8)));
typedef float  f32x4  __attribute__((ext_vector_type(4)));

__device__ __forceinline__ uint32_t rotl32(uint32_t x, int n) {
  return (x << n) | (x >> (32 - n));
}

// Threefry-2x32, 20 rounds — matches jax partitionable path (verified round 1)
__device__ __forceinline__ void tf2x32(uint32_t k0, uint32_t k1,
                                       uint32_t x0, uint32_t x1,
                                       uint32_t& o0, uint32_t& o1) {
  uint32_t k2 = k0 ^ k1 ^ 0x1BD11BDAu;
#define TFR(r) { x0 += x1; x1 = rotl32(x1, (r)); x1 ^= x0; }
  x0 += k0; x1 += k1;
  TFR(13) TFR(15) TFR(26) TFR(6)   x0 += k1; x1 += k2 + 1u;
  TFR(17) TFR(29) TFR(16) TFR(24)  x0 += k2; x1 += k0 + 2u;
  TFR(13) TFR(15) TFR(26) TFR(6)   x0 += k0; x1 += k1 + 3u;
  TFR(17) TFR(29) TFR(16) TFR(24)  x0 += k1; x1 += k2 + 4u;
  TFR(13) TFR(15) TFR(26) TFR(6)   x0 += k2; x1 += k0 + 5u;
#undef TFR
  o0 = x0; o1 = x1;
}

__global__ void conv_w(const float* __restrict__ W1, const float* __restrict__ W2,
                       const float* __restrict__ W3, const float* __restrict__ W4,
                       __bf16* __restrict__ ws) {
  int t = blockIdx.x * 256 + threadIdx.x;
  if (t < W2B_OFF) {
    int r = t / 96, c = t % 96;
    ws[t] = (c < KIN) ? (__bf16)W1[r * 66 + c] : (__bf16)0.0f;
  } else if (t < W3B_OFF) {
    ws[t] = (__bf16)W2[t - W2B_OFF];
  } else if (t < W4B_OFF) {
    ws[t] = (__bf16)W3[t - W3B_OFF];
  } else if (t < WS_ELEMS) {
    ws[t] = (__bf16)W4[t - W4B_OFF];
  }
}

__device__ __forceinline__ f32x4 mfma16(bf16x8 a, bf16x8 b, f32x4 c) {
  return __builtin_amdgcn_mfma_f32_16x16x32_bf16(a, b, c, 0, 0, 0);
}

// XOR-swizzled LDS byte offsets (col is a BYTE offset within the row)
__device__ __forceinline__ int swz256(int row, int col) { return row * 256 + (col ^ ((row & 15) << 4)); }
__device__ __forceinline__ int swz512(int row, int col) { return row * 512 + (col ^ ((row & 15) << 4)); }

// Empirical VGPR-cap model (6 data points): cap = pool/(waves/CU) with a hard
// ceiling at 128 for this kernel. (512,2)->128, (512,4)->64, (1024,4)->64,
// (512,1)->still 128 (ceiling). Design INSIDE the cap: 16 waves x 16 cols/wave
// => 84 VGPR of weights + ~40 working < 128, and 4 waves/SIMD occupancy.
__global__ void __launch_bounds__(BLKT, 1) model_kernel(
    const __bf16* __restrict__ ws,
    const float* __restrict__ b1, const float* __restrict__ b2,
    const float* __restrict__ b3, const float* __restrict__ b4,
    const float* __restrict__ x0p, const float* __restrict__ sp,
    const float* __restrict__ dpp, float* __restrict__ out)
{
  __shared__ __bf16 xb[16 * 128];        // MLP input (bf16, swizzled), 256B/row
  __shared__ __bf16 zA[16 * 256];        // L1 out (512B/row, swizzled)
  __shared__ __bf16 zB[16 * 256];        // L2 out
  __shared__ __bf16 scr[16 * 320];       // per-wave transpose scratch: 16 rows x 40B
  __shared__ float  psum[16][16][32];    // L4 partials [wave][row][dim], f32 (conflict-free)
  __shared__ uint32_t keys[NSTE - 1][2];
  __shared__ uint32_t jb[NSTE - 1][16];  // jump bitmask per (step, row)

  const int tid = threadIdx.x;
  const int r0  = blockIdx.x * ROWS;
  char* xbB = (char*)xb;
  char* zAB = (char*)zA;
  char* zBB = (char*)zB;

  const int wv  = tid >> 6;      // wave 0..15 -> N-cols [wv*16, wv*16+16)
  const int ln  = tid & 63;
  const int lr  = ln & 15;
  const int g   = ln >> 4;
  const int lk8 = g * 8;
  const int hc  = wv * 16 + lr;  // this lane's output column (h)
  const int er  = tid >> 5, ed = tid & 31;   // epilogue (row, dim), tid<512

  // ---------------- phase A: keys + zero xb ----------------
  if (tid < NSTE - 1) {
    uint32_t o0, o1;
    tf2x32(0u, 1234u, 0u, (uint32_t)tid, o0, o1);   // fold_in(key(1234), n)
    keys[tid][0] = o0; keys[tid][1] = o1;
  }
  for (int i = tid; i < 16 * 128; i += BLKT) xb[i] = (__bf16)0.0f;
  const float dp = dpp[0];
  __syncthreads();

  // ---------------- phase B: jump bits + state init + weight frags ----------------
  {
    // wave wv handles rows {2*(wv&7), 2*(wv&7)+1}; wv<8 -> steps 0..49, wv>=8 -> 50..98
    const int rr = 2 * (wv & 7) + (ln >> 5);
    const int dd = ln & 31;
    const uint32_t F = (uint32_t)((r0 + rr) * DIM_D + dd);
    const int n0 = (wv >> 3) * 50;
    const int n1 = (wv >> 3) ? (NSTE - 1) : 50;
    for (int n = n0; n < n1; ++n) {
      uint32_t o0, o1;
      tf2x32(keys[n][0], keys[n][1], 0u, F, o0, o1);
      const uint32_t bits = o0 ^ o1;
      const float uf = __uint_as_float((bits >> 9) | 0x3f800000u) - 1.0f;
      const unsigned long long m = __ballot(uf < 0.05f);
      if (ln == 0)       jb[n][rr] = (uint32_t)m;
      else if (ln == 32) jb[n][rr] = (uint32_t)(m >> 32);
    }
  }

  float V = 0.f, cr = 0.f, hv = 0.f, vsum = 0.f, hD = 0.f;
  float s_d = 1.f, b4d = 0.f;
  size_t ctrlb = 0, xbase = 0;
  if (tid < 512) {
    s_d = sp[ed];
    b4d = b4[ed];
    V  = x0p[ed];
    cr = x0p[33 + ed];
    hv = -logf(1.0f - V) / s_d;
    ctrlb = CTRL_OFF + (size_t)(r0 + er) * NSTE * DIM_D;
    xbase = X_OFF + (size_t)(r0 + er) * NSTE * 65;
    *(__bf16*)(xbB + swz256(er, ed * 2))        = (__bf16)V;
    *(__bf16*)(xbB + swz256(er, (33 + ed) * 2)) = (__bf16)cr;
    out[xbase + ed] = V;
    out[xbase + 33 + ed] = cr;
    out[ctrlb + (size_t)(NSTE - 1) * DIM_D + ed] = 0.0f;
    if (ed == 0) {
      hD = x0p[DIM_D] / dp;
      *(__bf16*)(xbB + swz256(er, 64))  = (__bf16)x0p[DIM_D];  // col 32 = Dv0
      *(__bf16*)(xbB + swz256(er, 130)) = (__bf16)0.0f;        // col 65 = t = 0
      out[xbase + 32] = x0p[DIM_D];
    }
  }

  // weight fragments — 84 VGPR, fully resident under the 128 cap
  bf16x8 w1f[3], w2f[8], w3f[8], w4t[2];
#pragma unroll
  for (int ks = 0; ks < 3; ++ks)
    w1f[ks] = *(const bf16x8*)(ws + W1B_OFF + hc * 96 + ks * 32 + lk8);
#pragma unroll
  for (int ks = 0; ks < 8; ++ks) {
    w2f[ks] = *(const bf16x8*)(ws + W2B_OFF + hc * 256 + ks * 32 + lk8);
    w3f[ks] = *(const bf16x8*)(ws + W3B_OFF + hc * 256 + ks * 32 + lk8);
  }
  {
    const bf16x8 z8 = bf16x8{};
#pragma unroll
    for (int t = 0; t < 2; ++t)
      w4t[t] = (g < 2) ? *(const bf16x8*)(ws + W4B_OFF + (t * 16 + lr) * 256 + wv * 16 + g * 8)
                       : z8;
  }
  const float bb1 = b1[hc];
  const float bb2 = b2[hc];
  const float bb3 = b3[hc];
  __syncthreads();

  float u_s = 0.f, V_s = 0.f, cr_s = 0.f, Dv_s = 0.f;

  // ---------------- 99 steps ----------------
  for (int n = 0; n < NSTE - 1; ++n) {
    // deferred global stores for step n-1 (drain hides under L1)
    if (n > 0 && tid < 512) {
      out[ctrlb + (size_t)(n - 1) * DIM_D + ed] = u_s;
      const size_t xo = xbase + (size_t)n * 65;
      out[xo + ed] = V_s;
      out[xo + 33 + ed] = cr_s;
      if (ed == 0) out[xo + 32] = Dv_s;
    }

    // ---- L1: xb (K=96) -> zA (wave's 16 cols) ----
    {
      f32x4 a0 = {bb1, bb1, bb1, bb1};
      bf16x8 af0 = *(const bf16x8*)(xbB + swz256(lr, g * 16));
      bf16x8 af1 = *(const bf16x8*)(xbB + swz256(lr, 64 + g * 16));
      bf16x8 af2 = *(const bf16x8*)(xbB + swz256(lr, 128 + g * 16));
      a0 = mfma16(af0, w1f[0], a0);
      a0 = mfma16(af1, w1f[1], a0);
      a0 = mfma16(af2, w1f[2], a0);
#pragma unroll
      for (int q = 0; q < 4; ++q)
        *(__bf16*)(zAB + swz512(g * 4 + q, hc * 2)) = (__bf16)fmaxf(a0[q], 0.0f);
    }
    __syncthreads();

    // ---- L2: zA -> zB ----
    {
      f32x4 a0 = {bb2, bb2, bb2, bb2};
#pragma unroll
      for (int ks = 0; ks < 8; ++ks) {
        bf16x8 af = *(const bf16x8*)(zAB + swz512(lr, ks * 64 + g * 16));
        a0 = mfma16(af, w2f[ks], a0);
      }
#pragma unroll
      for (int q = 0; q < 4; ++q)
        *(__bf16*)(zBB + swz512(g * 4 + q, hc * 2)) = (__bf16)fmaxf(a0[q], 0.0f);
    }
    __syncthreads();

    // ---- L3 (zB -> regs) fused with L4 (no block barrier between) ----
    {
      f32x4 a0 = {bb3, bb3, bb3, bb3};
#pragma unroll
      for (int ks = 0; ks < 8; ++ks) {
        bf16x8 af = *(const bf16x8*)(zBB + swz512(lr, ks * 64 + g * 16));
        a0 = mfma16(af, w3f[ks], a0);
      }
      // intra-wave transpose of this wave's 16 cols through private scratch
      // (40B row stride: read banks l*10 mod 32 all-distinct -> conflict-free)
      char* sw = (char*)scr + wv * 640;
#pragma unroll
      for (int q = 0; q < 4; ++q)
        *(__bf16*)(sw + (g * 4 + q) * 40 + lr * 2) = (__bf16)fmaxf(a0[q], 0.0f);
      asm volatile("s_waitcnt lgkmcnt(0)" ::: "memory");   // wave-local visibility
      bf16x8 a4 = bf16x8{};
      if (g < 2) a4 = *(const bf16x8*)(sw + lr * 40 + g * 16);
      f32x4 c0 = {0, 0, 0, 0}, c1 = {0, 0, 0, 0};
      c0 = mfma16(a4, w4t[0], c0);
      c1 = mfma16(a4, w4t[1], c1);
      // psum[wv][row][dim] f32: quarter-wave writes 64B contiguous (no conflict)
#pragma unroll
      for (int q = 0; q < 4; ++q) {
        psum[wv][g * 4 + q][lr]      = c0[q];
        psum[wv][g * 4 + q][16 + lr] = c1[q];
      }
    }
    __syncthreads();

    // ---- epilogue: u = sigmoid(b4 + sum_wv psum), jump, state update (regs) ----
    if (tid < 512) {
      vsum += V;                         // f-accumulation with pre-update V
      float up = b4d;
#pragma unroll
      for (int w = 0; w < 16; ++w) up += psum[w][er][ed];
      const float u = 1.0f / (1.0f + __expf(-up));
      const bool jump = (jb[n][er] >> ed) & 1;
      hv = jump ? 0.0f : (hv + DT_C);
      cr += jump ? u : 0.0f;
      V = 1.0f - __expf(-s_d * hv);
      *(__bf16*)(xbB + swz256(er, ed * 2))        = (__bf16)V;
      *(__bf16*)(xbB + swz256(er, (33 + ed) * 2)) = (__bf16)cr;
      if (ed == 0) {
        hD += DT_C;
        Dv_s = dp * hD;
        *(__bf16*)(xbB + swz256(er, 64))  = (__bf16)Dv_s;
        *(__bf16*)(xbB + swz256(er, 130)) = (__bf16)(DT_C * (float)(n + 1));
      }
      u_s = u; V_s = V; cr_s = cr;
    }
    __syncthreads();
  }

  // ---- final stores (step 98) + J ----
  if (tid < 512) {
    out[ctrlb + (size_t)(NSTE - 2) * DIM_D + ed] = u_s;
    const size_t xo = xbase + (size_t)(NSTE - 1) * 65;
    out[xo + ed] = V_s;
    out[xo + 33 + ed] = cr_s;
    if (ed == 0) out[xo + 32] = Dv_s;

    float c = cr, vv = vsum;
#pragma unroll
    for (int m = 1; m < 32; m <<= 1) {
      c  += __shfl_xor(c,  m, 32);
      vv += __shfl_xor(vv, m, 32);
    }
    if (ed == 0) out[J_OFF + (size_t)(r0 + er)] = DT_C * vv + c;
  }
}

extern "C" void kernel_launch(void* const* d_in, const int* in_sizes, int n_in,
                              void* d_out, int out_size, void* d_ws, size_t ws_size,
                              hipStream_t stream) {
  const float* W1 = (const float*)d_in[0];
  const float* b1 = (const float*)d_in[1];
  const float* W2 = (const float*)d_in[2];
  const float* b2 = (const float*)d_in[3];
  const float* W3 = (const float*)d_in[4];
  const float* b3 = (const float*)d_in[5];
  const float* W4 = (const float*)d_in[6];
  const float* b4 = (const float*)d_in[7];
  const float* x0 = (const float*)d_in[8];
  const float* s  = (const float*)d_in[9];
  const float* dp = (const float*)d_in[10];
  __bf16* ws = (__bf16*)d_ws;
  float* out = (float*)d_out;

  hipLaunchKernelGGL(conv_w, dim3(WS_ELEMS / 256), dim3(256), 0, stream, W1, W2, W3, W4, ws);
  hipLaunchKernelGGL(model_kernel, dim3(NBLK), dim3(BLKT), 0, stream,
                     ws, b1, b2, b3, b4, x0, s, dp, out);
}

// Round 8
// 616.833 us; speedup vs baseline: 1.2447x; 1.2447x over previous
//
#include <hip/hip_runtime.h>
#include <cstdint>
#include <cstddef>

#define DIM_D 32
#define KIN   66
#define NSTE  100
#define BATCHN 4096
#define ROWS  16
#define BLKT  512
#define NBLK  (BATCHN / ROWS)   // 256 blocks, 1 per CU

#define CTRL_OFF 0u
#define X_OFF 13107200u                 // BATCHN*NSTE*32
#define J_OFF 39731200u                 // X_OFF + BATCHN*NSTE*65

// bf16 weight arrays in d_ws (element offsets)
#define W1B_OFF 0            // [256][96] (cols 66..95 zero)
#define W2B_OFF 24576        // [256][256]
#define W3B_OFF 90112        // [256][256]
#define W4B_OFF 155648       // [32][256]
#define WS_ELEMS 163840

constexpr float DT_C = 0.01f;

typedef __bf16 bf16x8 __attribute__((ext_vector_type(8)));
typedef float  f32x4  __attribute__((ext_vector_type(4)));

__device__ __forceinline__ uint32_t rotl32(uint32_t x, int n) {
  return (x << n) | (x >> (32 - n));
}

// Threefry-2x32, 20 rounds — matches jax partitionable path (verified round 1)
__device__ __forceinline__ void tf2x32(uint32_t k0, uint32_t k1,
                                       uint32_t x0, uint32_t x1,
                                       uint32_t& o0, uint32_t& o1) {
  uint32_t k2 = k0 ^ k1 ^ 0x1BD11BDAu;
#define TFR(r) { x0 += x1; x1 = rotl32(x1, (r)); x1 ^= x0; }
  x0 += k0; x1 += k1;
  TFR(13) TFR(15) TFR(26) TFR(6)   x0 += k1; x1 += k2 + 1u;
  TFR(17) TFR(29) TFR(16) TFR(24)  x0 += k2; x1 += k0 + 2u;
  TFR(13) TFR(15) TFR(26) TFR(6)   x0 += k0; x1 += k1 + 3u;
  TFR(17) TFR(29) TFR(16) TFR(24)  x0 += k1; x1 += k2 + 4u;
  TFR(13) TFR(15) TFR(26) TFR(6)   x0 += k2; x1 += k0 + 5u;
#undef TFR
  o0 = x0; o1 = x1;
}

__global__ void conv_w(const float* __restrict__ W1, const float* __restrict__ W2,
                       const float* __restrict__ W3, const float* __restrict__ W4,
                       __bf16* __restrict__ ws) {
  int t = blockIdx.x * 256 + threadIdx.x;
  if (t < W2B_OFF) {
    int r = t / 96, c = t % 96;
    ws[t] = (c < KIN) ? (__bf16)W1[r * 66 + c] : (__bf16)0.0f;
  } else if (t < W3B_OFF) {
    ws[t] = (__bf16)W2[t - W2B_OFF];
  } else if (t < W4B_OFF) {
    ws[t] = (__bf16)W3[t - W3B_OFF];
  } else if (t < WS_ELEMS) {
    ws[t] = (__bf16)W4[t - W4B_OFF];
  }
}

__device__ __forceinline__ f32x4 mfma16(bf16x8 a, bf16x8 b, f32x4 c) {
  return __builtin_amdgcn_mfma_f32_16x16x32_bf16(a, b, c, 0, 0, 0);
}

// XOR-swizzled LDS byte offsets (col is a BYTE offset within the row)
__device__ __forceinline__ int swz256(int row, int col) { return row * 256 + (col ^ ((row & 15) << 4)); }
__device__ __forceinline__ int swz512(int row, int col) { return row * 512 + (col ^ ((row & 15) << 4)); }

// Strategy (r8): 512 thr, cap-128 accepted as hard. Resident: W2 frags (64) +
// W4 (8). W1/W3 streamed from L2 each step, issued one phase early so the
// vmcnt(0) drain at each barrier is already satisfied. Base pointer laundered
// per-iteration to block LICM (else compiler hoists all frag loads -> 160
// live -> spill, the r3/r4/r6 disease).
__global__ void __launch_bounds__(BLKT, 2) model_kernel(
    const __bf16* __restrict__ ws,
    const float* __restrict__ b1, const float* __restrict__ b2,
    const float* __restrict__ b3, const float* __restrict__ b4,
    const float* __restrict__ x0p, const float* __restrict__ sp,
    const float* __restrict__ dpp, float* __restrict__ out)
{
  __shared__ __bf16 xb[16 * 128];       // MLP input (bf16, swizzled), 256B/row
  __shared__ __bf16 zA[16 * 256];       // L1 out (512B/row, swizzled)
  __shared__ __bf16 zB[16 * 256];       // L2 out
  __shared__ __bf16 scr[8 * 16 * 40];   // per-wave L3->L4 transpose scratch (80B stride)
  __shared__ float  psum[8][16][32];    // L4 K-split partials
  __shared__ __bf16 ubuf[16][32];       // u (control) staging for step-top stores
  __shared__ uint32_t keys[NSTE - 1][2];
  __shared__ uint32_t jb[NSTE - 1][16]; // jump bitmask per (step, row)

  const int tid = threadIdx.x;
  const int r0  = blockIdx.x * ROWS;
  char* xbB = (char*)xb;
  char* zAB = (char*)zA;
  char* zBB = (char*)zB;

  const int wv  = tid >> 6;      // wave 0..7 -> N-cols [wv*32, wv*32+32)
  const int ln  = tid & 63;
  const int lr  = ln & 15;
  const int g   = ln >> 4;
  const int lk8 = g * 8;
  const int n1c0 = wv * 32 + lr;        // tile-0 output column
  const int n1c1 = wv * 32 + 16 + lr;   // tile-1 output column
  const int er  = tid >> 5, ed = tid & 31;   // (row, dim) — all 512 threads

  // ---------------- phase A: keys + zero xb ----------------
  if (tid < NSTE - 1) {
    uint32_t o0, o1;
    tf2x32(0u, 1234u, 0u, (uint32_t)tid, o0, o1);   // fold_in(key(1234), n)
    keys[tid][0] = o0; keys[tid][1] = o1;
  }
  for (int i = tid; i < 16 * 128; i += BLKT) xb[i] = (__bf16)0.0f;
  const float dp = dpp[0];
  __syncthreads();

  // ---------------- phase B: jump-bit precompute + state init ----------------
  {
    const int rr = 2 * wv + (ln >> 5);              // row 0..15 (2 rows per wave)
    const int dd = ln & 31;
    const uint32_t F = (uint32_t)((r0 + rr) * DIM_D + dd);
    for (int n = 0; n < NSTE - 1; ++n) {
      uint32_t o0, o1;
      tf2x32(keys[n][0], keys[n][1], 0u, F, o0, o1);
      const uint32_t bits = o0 ^ o1;
      const float uf = __uint_as_float((bits >> 9) | 0x3f800000u) - 1.0f;
      const unsigned long long m = __ballot(uf < 0.05f);
      if (ln == 0)       jb[n][rr] = (uint32_t)m;
      else if (ln == 32) jb[n][rr] = (uint32_t)(m >> 32);
    }
  }

  float cr, hv, vsum, Dv, s_d, b4d;
  uint32_t ctrlb, xbase;
  {
    s_d = sp[ed];
    b4d = b4[ed];
    const float V0 = x0p[ed];
    cr   = x0p[33 + ed];
    hv   = -logf(1.0f - V0) / s_d;
    vsum = V0;                                     // f-term of step 0
    Dv   = x0p[DIM_D];                             // d*hD0 = x0[32]
    ctrlb = CTRL_OFF + (uint32_t)(r0 + er) * NSTE * DIM_D;
    xbase = X_OFF + (uint32_t)(r0 + er) * NSTE * 65;
    *(__bf16*)(xbB + swz256(er, ed * 2))        = (__bf16)V0;
    *(__bf16*)(xbB + swz256(er, (33 + ed) * 2)) = (__bf16)cr;
    out[(size_t)(xbase + ed)] = V0;
    out[(size_t)(xbase + 33 + ed)] = cr;
    out[(size_t)(ctrlb + (NSTE - 1) * DIM_D + ed)] = 0.0f;
    if (ed == 0) {
      *(__bf16*)(xbB + swz256(er, 64))  = (__bf16)Dv;          // col 32 = Dv0
      *(__bf16*)(xbB + swz256(er, 130)) = (__bf16)0.0f;        // col 65 = t = 0
      out[(size_t)(xbase + 32)] = Dv;
    }
  }
  const float dpDT = dp * DT_C;

  // resident weight fragments: W2 (64 VGPR) + W4 (8 VGPR)
  bf16x8 w2f[2][8], w4t[2];
#pragma unroll
  for (int ks = 0; ks < 8; ++ks) {
    w2f[0][ks] = *(const bf16x8*)(ws + W2B_OFF + n1c0 * 256 + ks * 32 + lk8);
    w2f[1][ks] = *(const bf16x8*)(ws + W2B_OFF + n1c1 * 256 + ks * 32 + lk8);
  }
#pragma unroll
  for (int t = 0; t < 2; ++t)
    w4t[t] = *(const bf16x8*)(ws + W4B_OFF + (t * 16 + lr) * 256 + wv * 32 + lk8);

  // prologue W1 fragments (rotating: reloaded each epilogue for next step)
  bf16x8 w1c0[3], w1c1[3];
#pragma unroll
  for (int ks = 0; ks < 3; ++ks) {
    w1c0[ks] = *(const bf16x8*)(ws + W1B_OFF + n1c0 * 96 + ks * 32 + lk8);
    w1c1[ks] = *(const bf16x8*)(ws + W1B_OFF + n1c1 * 96 + ks * 32 + lk8);
  }
  __syncthreads();

  uintptr_t wsu = (uintptr_t)ws;    // laundered per-iteration (blocks LICM)

  // ---------------- 99 steps ----------------
  for (int n = 0; n < NSTE - 1; ++n) {
    asm volatile("" : "+s"(wsu));
    const __bf16* wsl = (const __bf16*)wsu;

    // ---- (A) store step n-1 results (from LDS/regs; drain hides under L1) ----
    if (n > 0) {
      const float uo = (float)ubuf[er][ed];
      const float Vo = (float)*(const __bf16*)(xbB + swz256(er, ed * 2));
      vsum += Vo;                                   // f-term of step n
      out[(size_t)(ctrlb + (uint32_t)(n - 1) * DIM_D + ed)] = uo;
      const uint32_t xo = xbase + (uint32_t)n * 65;
      out[(size_t)(xo + ed)] = Vo;
      out[(size_t)(xo + 33 + ed)] = cr;             // cr reg is f32-exact
      if (ed == 0) out[(size_t)(xo + 32)] = Dv;
    }

    // ---- (B) L1: xb (K=96) -> zA, consuming w1c loaded last epilogue ----
    {
      const float bb1_0 = b1[n1c0], bb1_1 = b1[n1c1];
      f32x4 a0 = {0, 0, 0, 0}, a1 = {0, 0, 0, 0};
      bf16x8 af0 = *(const bf16x8*)(xbB + swz256(lr, g * 16));
      bf16x8 af1 = *(const bf16x8*)(xbB + swz256(lr, 64 + g * 16));
      bf16x8 af2 = *(const bf16x8*)(xbB + swz256(lr, 128 + g * 16));
      a0 = mfma16(af0, w1c0[0], a0);  a1 = mfma16(af0, w1c1[0], a1);
      a0 = mfma16(af1, w1c0[1], a0);  a1 = mfma16(af1, w1c1[1], a1);
      a0 = mfma16(af2, w1c0[2], a0);  a1 = mfma16(af2, w1c1[2], a1);
#pragma unroll
      for (int q = 0; q < 4; ++q) {
        const int row = g * 4 + q;
        *(__bf16*)(zAB + swz512(row, n1c0 * 2)) = (__bf16)fmaxf(a0[q] + bb1_0, 0.0f);
        *(__bf16*)(zAB + swz512(row, n1c1 * 2)) = (__bf16)fmaxf(a1[q] + bb1_1, 0.0f);
      }
    }
    __syncthreads();

    // ---- (C) L2: zA -> zB (W2 resident); stream W3 (issue-early) ----
    bf16x8 w3a[8], w3b[8];
    {
      const bf16x8* p3a = (const bf16x8*)(wsl + W3B_OFF + n1c0 * 256 + lk8);
#pragma unroll
      for (int ks = 0; ks < 8; ++ks) w3a[ks] = p3a[ks * 4];   // tile-0 W3: issue at C-start
      const float bb2_0 = b2[n1c0], bb2_1 = b2[n1c1];
      f32x4 a0 = {0, 0, 0, 0}, a1 = {0, 0, 0, 0};
#pragma unroll
      for (int ks = 0; ks < 4; ++ks) {
        bf16x8 af = *(const bf16x8*)(zAB + swz512(lr, ks * 64 + g * 16));
        a0 = mfma16(af, w2f[0][ks], a0);
        a1 = mfma16(af, w2f[1][ks], a1);
      }
      const bf16x8* p3b = (const bf16x8*)(wsl + W3B_OFF + n1c1 * 256 + lk8);
#pragma unroll
      for (int ks = 0; ks < 8; ++ks) w3b[ks] = p3b[ks * 4];   // tile-1 W3: issue at C-mid
#pragma unroll
      for (int ks = 4; ks < 8; ++ks) {
        bf16x8 af = *(const bf16x8*)(zAB + swz512(lr, ks * 64 + g * 16));
        a0 = mfma16(af, w2f[0][ks], a0);
        a1 = mfma16(af, w2f[1][ks], a1);
      }
#pragma unroll
      for (int q = 0; q < 4; ++q) {
        const int row = g * 4 + q;
        *(__bf16*)(zBB + swz512(row, n1c0 * 2)) = (__bf16)fmaxf(a0[q] + bb2_0, 0.0f);
        *(__bf16*)(zBB + swz512(row, n1c1 * 2)) = (__bf16)fmaxf(a1[q] + bb2_1, 0.0f);
      }
    }
    __syncthreads();

    // ---- (D) L3 (two passes over zB, streamed W3) fused with L4 ----
    {
      const float bb3_0 = b3[n1c0], bb3_1 = b3[n1c1];
      f32x4 a0 = {0, 0, 0, 0}, a1 = {0, 0, 0, 0};
#pragma unroll
      for (int ks = 0; ks < 8; ++ks) {
        bf16x8 af = *(const bf16x8*)(zBB + swz512(lr, ks * 64 + g * 16));
        a0 = mfma16(af, w3a[ks], a0);
      }
#pragma unroll
      for (int ks = 0; ks < 8; ++ks) {
        bf16x8 af = *(const bf16x8*)(zBB + swz512(lr, ks * 64 + g * 16));
        a1 = mfma16(af, w3b[ks], a1);
      }
      // intra-wave transpose of this wave's 32 cols through private scratch
      char* sw = (char*)scr + wv * 1280;
#pragma unroll
      for (int q = 0; q < 4; ++q) {
        const int row = g * 4 + q;
        *(__bf16*)(sw + row * 80 + lr * 2)      = (__bf16)fmaxf(a0[q] + bb3_0, 0.0f);
        *(__bf16*)(sw + row * 80 + 32 + lr * 2) = (__bf16)fmaxf(a1[q] + bb3_1, 0.0f);
      }
      asm volatile("s_waitcnt lgkmcnt(0)" ::: "memory");   // wave-local visibility
      const bf16x8 a4 = *(const bf16x8*)(sw + lr * 80 + g * 16);
      f32x4 c0 = {0, 0, 0, 0}, c1 = {0, 0, 0, 0};
      c0 = mfma16(a4, w4t[0], c0);
      c1 = mfma16(a4, w4t[1], c1);
#pragma unroll
      for (int q = 0; q < 4; ++q) {
        psum[wv][g * 4 + q][lr]      = c0[q];
        psum[wv][g * 4 + q][16 + lr] = c1[q];
      }
    }
    __syncthreads();

    // ---- (E) epilogue: u, jump, state update; reload W1 for next step ----
    {
#pragma unroll
      for (int ks = 0; ks < 3; ++ks) {            // issue-early: consumed next (B)
        w1c0[ks] = *(const bf16x8*)(wsl + W1B_OFF + n1c0 * 96 + ks * 32 + lk8);
        w1c1[ks] = *(const bf16x8*)(wsl + W1B_OFF + n1c1 * 96 + ks * 32 + lk8);
      }
      float up = b4d;
#pragma unroll
      for (int w = 0; w < 8; ++w) up += psum[w][er][ed];
      const float u = 1.0f / (1.0f + __expf(-up));
      const bool jump = (jb[n][er] >> ed) & 1;
      hv = jump ? 0.0f : (hv + DT_C);
      cr += jump ? u : 0.0f;
      const float V = 1.0f - __expf(-s_d * hv);
      ubuf[er][ed] = (__bf16)u;
      *(__bf16*)(xbB + swz256(er, ed * 2))        = (__bf16)V;
      *(__bf16*)(xbB + swz256(er, (33 + ed) * 2)) = (__bf16)cr;
      if (ed == 0) {
        Dv += dpDT;
        *(__bf16*)(xbB + swz256(er, 64))  = (__bf16)Dv;
        *(__bf16*)(xbB + swz256(er, 130)) = (__bf16)(DT_C * (float)(n + 1));
      }
    }
    __syncthreads();
  }

  // ---- final stores (step 98) + J ----
  {
    const float uo = (float)ubuf[er][ed];
    const float Vo = (float)*(const __bf16*)(xbB + swz256(er, ed * 2));
    out[(size_t)(ctrlb + (uint32_t)(NSTE - 2) * DIM_D + ed)] = uo;
    const uint32_t xo = xbase + (uint32_t)(NSTE - 1) * 65;
    out[(size_t)(xo + ed)] = Vo;
    out[(size_t)(xo + 33 + ed)] = cr;
    if (ed == 0) out[(size_t)(xo + 32)] = Dv;

    float c = cr, vv = vsum;
#pragma unroll
    for (int m = 1; m < 32; m <<= 1) {
      c  += __shfl_xor(c,  m, 32);
      vv += __shfl_xor(vv, m, 32);
    }
    if (ed == 0) out[(size_t)(J_OFF + (uint32_t)(r0 + er))] = DT_C * vv + c;
  }
}

extern "C" void kernel_launch(void* const* d_in, const int* in_sizes, int n_in,
                              void* d_out, int out_size, void* d_ws, size_t ws_size,
                              hipStream_t stream) {
  const float* W1 = (const float*)d_in[0];
  const float* b1 = (const float*)d_in[1];
  const float* W2 = (const float*)d_in[2];
  const float* b2 = (const float*)d_in[3];
  const float* W3 = (const float*)d_in[4];
  const float* b3 = (const float*)d_in[5];
  const float* W4 = (const float*)d_in[6];
  const float* b4 = (const float*)d_in[7];
  const float* x0 = (const float*)d_in[8];
  const float* s  = (const float*)d_in[9];
  const float* dp = (const float*)d_in[10];
  __bf16* ws = (__bf16*)d_ws;
  float* out = (float*)d_out;

  hipLaunchKernelGGL(conv_w, dim3(WS_ELEMS / 256), dim3(256), 0, stream, W1, W2, W3, W4, ws);
  hipLaunchKernelGGL(model_kernel, dim3(NBLK), dim3(BLKT), 0, stream,
                     ws, b1, b2, b3, b4, x0, s, dp, out);
}

// Round 9
// 614.779 us; speedup vs baseline: 1.2488x; 1.0033x over previous
//
#include <hip/hip_runtime.h>
#include <cstdint>
#include <cstddef>

#define DIM_D 32
#define KIN   66
#define NSTE  100
#define BATCHN 4096
#define ROWS  16
#define BLKT  512
#define NBLK  (BATCHN / ROWS)   // 256 blocks, 1 per CU

#define CTRL_OFF 0u
#define X_OFF 13107200u                 // BATCHN*NSTE*32
#define J_OFF 39731200u                 // X_OFF + BATCHN*NSTE*65

// bf16 weight arrays in d_ws (element offsets)
#define W1B_OFF 0            // [256][96] (cols 66..95 zero)
#define W2B_OFF 24576        // [256][256]
#define W3B_OFF 90112        // [256][256]
#define W4B_OFF 155648       // [32][256]
#define WS_ELEMS 163840

constexpr float DT_C = 0.01f;

typedef __bf16 bf16x8 __attribute__((ext_vector_type(8)));
typedef float  f32x4  __attribute__((ext_vector_type(4)));

// Raw barrier: LDS-visibility only (lgkmcnt(0)), NO vmcnt drain. This is the
// whole point of round 9: __syncthreads() = "s_waitcnt vmcnt(0) lgkmcnt(0);
// s_barrier" which drains the streamed W1/W3 loads and the output stores at
// every phase boundary (r8: 616us, MfmaUtil 8.5%). With raw barriers the
// compiler's counted vmcnt at first-use does the synchronization, and stores
// float across barriers. Empty clobber-asm on both sides fences code motion.
#define BAR() do {                                              \
    asm volatile("s_waitcnt lgkmcnt(0)" ::: "memory");          \
    __builtin_amdgcn_s_barrier();                               \
    asm volatile("" ::: "memory");                              \
  } while (0)

__device__ __forceinline__ uint32_t rotl32(uint32_t x, int n) {
  return (x << n) | (x >> (32 - n));
}

// Threefry-2x32, 20 rounds — matches jax partitionable path (verified round 1)
__device__ __forceinline__ void tf2x32(uint32_t k0, uint32_t k1,
                                       uint32_t x0, uint32_t x1,
                                       uint32_t& o0, uint32_t& o1) {
  uint32_t k2 = k0 ^ k1 ^ 0x1BD11BDAu;
#define TFR(r) { x0 += x1; x1 = rotl32(x1, (r)); x1 ^= x0; }
  x0 += k0; x1 += k1;
  TFR(13) TFR(15) TFR(26) TFR(6)   x0 += k1; x1 += k2 + 1u;
  TFR(17) TFR(29) TFR(16) TFR(24)  x0 += k2; x1 += k0 + 2u;
  TFR(13) TFR(15) TFR(26) TFR(6)   x0 += k0; x1 += k1 + 3u;
  TFR(17) TFR(29) TFR(16) TFR(24)  x0 += k1; x1 += k2 + 4u;
  TFR(13) TFR(15) TFR(26) TFR(6)   x0 += k2; x1 += k0 + 5u;
#undef TFR
  o0 = x0; o1 = x1;
}

__global__ void conv_w(const float* __restrict__ W1, const float* __restrict__ W2,
                       const float* __restrict__ W3, const float* __restrict__ W4,
                       __bf16* __restrict__ ws) {
  int t = blockIdx.x * 256 + threadIdx.x;
  if (t < W2B_OFF) {
    int r = t / 96, c = t % 96;
    ws[t] = (c < KIN) ? (__bf16)W1[r * 66 + c] : (__bf16)0.0f;
  } else if (t < W3B_OFF) {
    ws[t] = (__bf16)W2[t - W2B_OFF];
  } else if (t < W4B_OFF) {
    ws[t] = (__bf16)W3[t - W3B_OFF];
  } else if (t < WS_ELEMS) {
    ws[t] = (__bf16)W4[t - W4B_OFF];
  }
}

__device__ __forceinline__ f32x4 mfma16(bf16x8 a, bf16x8 b, f32x4 c) {
  return __builtin_amdgcn_mfma_f32_16x16x32_bf16(a, b, c, 0, 0, 0);
}

// XOR-swizzled LDS byte offsets (col is a BYTE offset within the row)
__device__ __forceinline__ int swz256(int row, int col) { return row * 256 + (col ^ ((row & 15) << 4)); }
__device__ __forceinline__ int swz512(int row, int col) { return row * 512 + (col ^ ((row & 15) << 4)); }

__global__ void __launch_bounds__(BLKT, 2) model_kernel(
    const __bf16* __restrict__ ws,
    const float* __restrict__ b1, const float* __restrict__ b2,
    const float* __restrict__ b3, const float* __restrict__ b4,
    const float* __restrict__ x0p, const float* __restrict__ sp,
    const float* __restrict__ dpp, float* __restrict__ out)
{
  __shared__ __bf16 xb[16 * 128];       // MLP input (bf16, swizzled), 256B/row
  __shared__ __bf16 zA[16 * 256];       // L1 out (512B/row, swizzled)
  __shared__ __bf16 zB[16 * 256];       // L2 out
  __shared__ __bf16 scr[8 * 16 * 40];   // per-wave L3->L4 transpose scratch (80B stride)
  __shared__ float  psum[8][16][32];    // L4 K-split partials
  __shared__ __bf16 ubuf[16][32];       // u (control) staging for step-top stores
  __shared__ uint32_t keys[NSTE - 1][2];
  __shared__ uint32_t jb[NSTE - 1][16]; // jump bitmask per (step, row)

  const int tid = threadIdx.x;
  const int r0  = blockIdx.x * ROWS;
  char* xbB = (char*)xb;
  char* zAB = (char*)zA;
  char* zBB = (char*)zB;

  const int wv  = tid >> 6;      // wave 0..7 -> N-cols [wv*32, wv*32+32)
  const int ln  = tid & 63;
  const int lr  = ln & 15;
  const int g   = ln >> 4;
  const int lk8 = g * 8;
  const int n1c0 = wv * 32 + lr;        // tile-0 output column
  const int n1c1 = wv * 32 + 16 + lr;   // tile-1 output column
  const int er  = tid >> 5, ed = tid & 31;   // (row, dim) — all 512 threads

  // ---------------- phase A: keys + zero xb ----------------
  if (tid < NSTE - 1) {
    uint32_t o0, o1;
    tf2x32(0u, 1234u, 0u, (uint32_t)tid, o0, o1);   // fold_in(key(1234), n)
    keys[tid][0] = o0; keys[tid][1] = o1;
  }
  for (int i = tid; i < 16 * 128; i += BLKT) xb[i] = (__bf16)0.0f;
  const float dp = dpp[0];
  __syncthreads();

  // ---------------- phase B: jump-bit precompute + state init ----------------
  {
    const int rr = 2 * wv + (ln >> 5);              // row 0..15 (2 rows per wave)
    const int dd = ln & 31;
    const uint32_t F = (uint32_t)((r0 + rr) * DIM_D + dd);
    for (int n = 0; n < NSTE - 1; ++n) {
      uint32_t o0, o1;
      tf2x32(keys[n][0], keys[n][1], 0u, F, o0, o1);
      const uint32_t bits = o0 ^ o1;
      const float uf = __uint_as_float((bits >> 9) | 0x3f800000u) - 1.0f;
      const unsigned long long m = __ballot(uf < 0.05f);
      if (ln == 0)       jb[n][rr] = (uint32_t)m;
      else if (ln == 32) jb[n][rr] = (uint32_t)(m >> 32);
    }
  }

  float cr, hv, vsum, Dv, s_d, b4d;
  uint32_t ctrlb, xbase;
  {
    s_d = sp[ed];
    b4d = b4[ed];
    const float V0 = x0p[ed];
    cr   = x0p[33 + ed];
    hv   = -logf(1.0f - V0) / s_d;
    vsum = V0;                                     // f-term of step 0
    Dv   = x0p[DIM_D];                             // d*hD0 = x0[32]
    ctrlb = CTRL_OFF + (uint32_t)(r0 + er) * NSTE * DIM_D;
    xbase = X_OFF + (uint32_t)(r0 + er) * NSTE * 65;
    *(__bf16*)(xbB + swz256(er, ed * 2))        = (__bf16)V0;
    *(__bf16*)(xbB + swz256(er, (33 + ed) * 2)) = (__bf16)cr;
    out[(size_t)(xbase + ed)] = V0;
    out[(size_t)(xbase + 33 + ed)] = cr;
    out[(size_t)(ctrlb + (NSTE - 1) * DIM_D + ed)] = 0.0f;
    if (ed == 0) {
      *(__bf16*)(xbB + swz256(er, 64))  = (__bf16)Dv;          // col 32 = Dv0
      *(__bf16*)(xbB + swz256(er, 130)) = (__bf16)0.0f;        // col 65 = t = 0
      out[(size_t)(xbase + 32)] = Dv;
    }
  }
  const float dpDT = dp * DT_C;

  // resident weight fragments: W2 (64 VGPR) + W4 (8 VGPR)
  bf16x8 w2f[2][8], w4t[2];
#pragma unroll
  for (int ks = 0; ks < 8; ++ks) {
    w2f[0][ks] = *(const bf16x8*)(ws + W2B_OFF + n1c0 * 256 + ks * 32 + lk8);
    w2f[1][ks] = *(const bf16x8*)(ws + W2B_OFF + n1c1 * 256 + ks * 32 + lk8);
  }
#pragma unroll
  for (int t = 0; t < 2; ++t)
    w4t[t] = *(const bf16x8*)(ws + W4B_OFF + (t * 16 + lr) * 256 + wv * 32 + lk8);

  // prologue W1 fragments (rotating: reloaded each epilogue for next step)
  bf16x8 w1c0[3], w1c1[3];
#pragma unroll
  for (int ks = 0; ks < 3; ++ks) {
    w1c0[ks] = *(const bf16x8*)(ws + W1B_OFF + n1c0 * 96 + ks * 32 + lk8);
    w1c1[ks] = *(const bf16x8*)(ws + W1B_OFF + n1c1 * 96 + ks * 32 + lk8);
  }
  __syncthreads();

  uintptr_t wsu = (uintptr_t)ws;    // laundered per-iteration (blocks LICM)

  // ---------------- 99 steps ----------------
  for (int n = 0; n < NSTE - 1; ++n) {
    asm volatile("" : "+s"(wsu));
    const __bf16* wsl = (const __bf16*)wsu;

    // ---- (A) store step n-1 results (stores float across raw barriers) ----
    if (n > 0) {
      const float uo = (float)ubuf[er][ed];
      const float Vo = (float)*(const __bf16*)(xbB + swz256(er, ed * 2));
      vsum += Vo;                                   // f-term of step n
      out[(size_t)(ctrlb + (uint32_t)(n - 1) * DIM_D + ed)] = uo;
      const uint32_t xo = xbase + (uint32_t)n * 65;
      out[(size_t)(xo + ed)] = Vo;
      out[(size_t)(xo + 33 + ed)] = cr;             // cr reg is f32-exact
      if (ed == 0) out[(size_t)(xo + 32)] = Dv;
    }

    // ---- (B) L1: xb (K=96) -> zA, consuming w1c loaded last epilogue ----
    {
      const float bb1_0 = b1[n1c0], bb1_1 = b1[n1c1];
      f32x4 a0 = {0, 0, 0, 0}, a1 = {0, 0, 0, 0};
      bf16x8 af0 = *(const bf16x8*)(xbB + swz256(lr, g * 16));
      bf16x8 af1 = *(const bf16x8*)(xbB + swz256(lr, 64 + g * 16));
      bf16x8 af2 = *(const bf16x8*)(xbB + swz256(lr, 128 + g * 16));
      a0 = mfma16(af0, w1c0[0], a0);  a1 = mfma16(af0, w1c1[0], a1);
      a0 = mfma16(af1, w1c0[1], a0);  a1 = mfma16(af1, w1c1[1], a1);
      a0 = mfma16(af2, w1c0[2], a0);  a1 = mfma16(af2, w1c1[2], a1);
#pragma unroll
      for (int q = 0; q < 4; ++q) {
        const int row = g * 4 + q;
        *(__bf16*)(zAB + swz512(row, n1c0 * 2)) = (__bf16)fmaxf(a0[q] + bb1_0, 0.0f);
        *(__bf16*)(zAB + swz512(row, n1c1 * 2)) = (__bf16)fmaxf(a1[q] + bb1_1, 0.0f);
      }
    }
    BAR();

    // ---- (C) L2: zA -> zB (W2 resident); stream W3 (issue-early) ----
    bf16x8 w3a[8], w3b[8];
    {
      const bf16x8* p3a = (const bf16x8*)(wsl + W3B_OFF + n1c0 * 256 + lk8);
#pragma unroll
      for (int ks = 0; ks < 8; ++ks) w3a[ks] = p3a[ks * 4];   // tile-0 W3: issue at C-start
      const float bb2_0 = b2[n1c0], bb2_1 = b2[n1c1];
      f32x4 a0 = {0, 0, 0, 0}, a1 = {0, 0, 0, 0};
#pragma unroll
      for (int ks = 0; ks < 4; ++ks) {
        bf16x8 af = *(const bf16x8*)(zAB + swz512(lr, ks * 64 + g * 16));
        a0 = mfma16(af, w2f[0][ks], a0);
        a1 = mfma16(af, w2f[1][ks], a1);
      }
      const bf16x8* p3b = (const bf16x8*)(wsl + W3B_OFF + n1c1 * 256 + lk8);
#pragma unroll
      for (int ks = 0; ks < 8; ++ks) w3b[ks] = p3b[ks * 4];   // tile-1 W3: issue at C-mid
#pragma unroll
      for (int ks = 4; ks < 8; ++ks) {
        bf16x8 af = *(const bf16x8*)(zAB + swz512(lr, ks * 64 + g * 16));
        a0 = mfma16(af, w2f[0][ks], a0);
        a1 = mfma16(af, w2f[1][ks], a1);
      }
#pragma unroll
      for (int q = 0; q < 4; ++q) {
        const int row = g * 4 + q;
        *(__bf16*)(zBB + swz512(row, n1c0 * 2)) = (__bf16)fmaxf(a0[q] + bb2_0, 0.0f);
        *(__bf16*)(zBB + swz512(row, n1c1 * 2)) = (__bf16)fmaxf(a1[q] + bb2_1, 0.0f);
      }
    }
    BAR();

    // ---- (D) L3 (two passes over zB, streamed W3) fused with L4 ----
    {
      const float bb3_0 = b3[n1c0], bb3_1 = b3[n1c1];
      f32x4 a0 = {0, 0, 0, 0}, a1 = {0, 0, 0, 0};
#pragma unroll
      for (int ks = 0; ks < 8; ++ks) {
        bf16x8 af = *(const bf16x8*)(zBB + swz512(lr, ks * 64 + g * 16));
        a0 = mfma16(af, w3a[ks], a0);
      }
#pragma unroll
      for (int ks = 0; ks < 8; ++ks) {
        bf16x8 af = *(const bf16x8*)(zBB + swz512(lr, ks * 64 + g * 16));
        a1 = mfma16(af, w3b[ks], a1);
      }
      // intra-wave transpose of this wave's 32 cols through private scratch
      char* sw = (char*)scr + wv * 1280;
#pragma unroll
      for (int q = 0; q < 4; ++q) {
        const int row = g * 4 + q;
        *(__bf16*)(sw + row * 80 + lr * 2)      = (__bf16)fmaxf(a0[q] + bb3_0, 0.0f);
        *(__bf16*)(sw + row * 80 + 32 + lr * 2) = (__bf16)fmaxf(a1[q] + bb3_1, 0.0f);
      }
      asm volatile("s_waitcnt lgkmcnt(0)" ::: "memory");   // wave-local visibility
      const bf16x8 a4 = *(const bf16x8*)(sw + lr * 80 + g * 16);
      f32x4 c0 = {0, 0, 0, 0}, c1 = {0, 0, 0, 0};
      c0 = mfma16(a4, w4t[0], c0);
      c1 = mfma16(a4, w4t[1], c1);
#pragma unroll
      for (int q = 0; q < 4; ++q) {
        psum[wv][g * 4 + q][lr]      = c0[q];
        psum[wv][g * 4 + q][16 + lr] = c1[q];
      }
    }
    BAR();

    // ---- (E) epilogue: u, jump, state update; reload W1 for next step ----
    {
#pragma unroll
      for (int ks = 0; ks < 3; ++ks) {            // issue-early: consumed next (B)
        w1c0[ks] = *(const bf16x8*)(wsl + W1B_OFF + n1c0 * 96 + ks * 32 + lk8);
        w1c1[ks] = *(const bf16x8*)(wsl + W1B_OFF + n1c1 * 96 + ks * 32 + lk8);
      }
      float up = b4d;
#pragma unroll
      for (int w = 0; w < 8; ++w) up += psum[w][er][ed];
      const float u = 1.0f / (1.0f + __expf(-up));
      const bool jump = (jb[n][er] >> ed) & 1;
      hv = jump ? 0.0f : (hv + DT_C);
      cr += jump ? u : 0.0f;
      const float V = 1.0f - __expf(-s_d * hv);
      ubuf[er][ed] = (__bf16)u;
      *(__bf16*)(xbB + swz256(er, ed * 2))        = (__bf16)V;
      *(__bf16*)(xbB + swz256(er, (33 + ed) * 2)) = (__bf16)cr;
      if (ed == 0) {
        Dv += dpDT;
        *(__bf16*)(xbB + swz256(er, 64))  = (__bf16)Dv;
        *(__bf16*)(xbB + swz256(er, 130)) = (__bf16)(DT_C * (float)(n + 1));
      }
    }
    BAR();
  }

  // ---- final stores (step 98) + J ----
  {
    const float uo = (float)ubuf[er][ed];
    const float Vo = (float)*(const __bf16*)(xbB + swz256(er, ed * 2));
    out[(size_t)(ctrlb + (uint32_t)(NSTE - 2) * DIM_D + ed)] = uo;
    const uint32_t xo = xbase + (uint32_t)(NSTE - 1) * 65;
    out[(size_t)(xo + ed)] = Vo;
    out[(size_t)(xo + 33 + ed)] = cr;
    if (ed == 0) out[(size_t)(xo + 32)] = Dv;

    float c = cr, vv = vsum;
#pragma unroll
    for (int m = 1; m < 32; m <<= 1) {
      c  += __shfl_xor(c,  m, 32);
      vv += __shfl_xor(vv, m, 32);
    }
    if (ed == 0) out[(size_t)(J_OFF + (uint32_t)(r0 + er))] = DT_C * vv + c;
  }
}

extern "C" void kernel_launch(void* const* d_in, const int* in_sizes, int n_in,
                              void* d_out, int out_size, void* d_ws, size_t ws_size,
                              hipStream_t stream) {
  const float* W1 = (const float*)d_in[0];
  const float* b1 = (const float*)d_in[1];
  const float* W2 = (const float*)d_in[2];
  const float* b2 = (const float*)d_in[3];
  const float* W3 = (const float*)d_in[4];
  const float* b3 = (const float*)d_in[5];
  const float* W4 = (const float*)d_in[6];
  const float* b4 = (const float*)d_in[7];
  const float* x0 = (const float*)d_in[8];
  const float* s  = (const float*)d_in[9];
  const float* dp = (const float*)d_in[10];
  __bf16* ws = (__bf16*)d_ws;
  float* out = (float*)d_out;

  hipLaunchKernelGGL(conv_w, dim3(WS_ELEMS / 256), dim3(256), 0, stream, W1, W2, W3, W4, ws);
  hipLaunchKernelGGL(model_kernel, dim3(NBLK), dim3(BLKT), 0, stream,
                     ws, b1, b2, b3, b4, x0, s, dp, out);
}

// Round 10
// 501.017 us; speedup vs baseline: 1.5324x; 1.2271x over previous
//
#include <hip/hip_runtime.h>
#include <cstdint>
#include <cstddef>

#define DIM_D 32
#define KIN   66
#define NSTE  100
#define BATCHN 4096
#define ROWS  8
#define BLKT  512
#define NBLK  (BATCHN / ROWS)   // 512 blocks -> 2 blocks/CU, 4 waves/SIMD

#define CTRL_OFF 0
#define X_OFF ((size_t)BATCHN * NSTE * DIM_D)
#define J_OFF (X_OFF + (size_t)BATCHN * NSTE * 65)

// bf16 weight arrays in d_ws (element offsets)
#define W1B_OFF 0            // [256][96] (cols 66..95 zero)
#define W2B_OFF 24576        // [256][256]
#define W3B_OFF 90112        // [256][256]
#define W4B_OFF 155648       // [32][256]
#define WS_ELEMS 163840

constexpr float DT_C = 0.01f;

typedef __bf16 bf16x8 __attribute__((ext_vector_type(8)));
typedef float  f32x4  __attribute__((ext_vector_type(4)));

__device__ __forceinline__ uint32_t rotl32(uint32_t x, int n) {
  return (x << n) | (x >> (32 - n));
}

// Threefry-2x32, 20 rounds — matches jax partitionable path (verified round 1)
__device__ __forceinline__ void tf2x32(uint32_t k0, uint32_t k1,
                                       uint32_t x0, uint32_t x1,
                                       uint32_t& o0, uint32_t& o1) {
  uint32_t k2 = k0 ^ k1 ^ 0x1BD11BDAu;
#define TFR(r) { x0 += x1; x1 = rotl32(x1, (r)); x1 ^= x0; }
  x0 += k0; x1 += k1;
  TFR(13) TFR(15) TFR(26) TFR(6)   x0 += k1; x1 += k2 + 1u;
  TFR(17) TFR(29) TFR(16) TFR(24)  x0 += k2; x1 += k0 + 2u;
  TFR(13) TFR(15) TFR(26) TFR(6)   x0 += k0; x1 += k1 + 3u;
  TFR(17) TFR(29) TFR(16) TFR(24)  x0 += k1; x1 += k2 + 4u;
  TFR(13) TFR(15) TFR(26) TFR(6)   x0 += k2; x1 += k0 + 5u;
#undef TFR
  o0 = x0; o1 = x1;
}

__global__ void conv_w(const float* __restrict__ W1, const float* __restrict__ W2,
                       const float* __restrict__ W3, const float* __restrict__ W4,
                       __bf16* __restrict__ ws) {
  int t = blockIdx.x * 256 + threadIdx.x;
  if (t < W2B_OFF) {
    int r = t / 96, c = t % 96;
    ws[t] = (c < KIN) ? (__bf16)W1[r * 66 + c] : (__bf16)0.0f;
  } else if (t < W3B_OFF) {
    ws[t] = (__bf16)W2[t - W2B_OFF];
  } else if (t < W4B_OFF) {
    ws[t] = (__bf16)W3[t - W3B_OFF];
  } else if (t < WS_ELEMS) {
    ws[t] = (__bf16)W4[t - W4B_OFF];
  }
}

__device__ __forceinline__ f32x4 mfma16(bf16x8 a, bf16x8 b, f32x4 c) {
  return __builtin_amdgcn_mfma_f32_16x16x32_bf16(a, b, c, 0, 0, 0);
}

// XOR-swizzled LDS byte offsets (col is a BYTE offset within the row)
__device__ __forceinline__ int swz256(int row, int col) { return row * 256 + (col ^ ((row & 15) << 4)); }
__device__ __forceinline__ int swz512(int row, int col) { return row * 512 + (col ^ ((row & 15) << 4)); }

// r10 = the proven 260us body (r1 proposal) with exactly two deltas:
//   (1) ROWS 16->8, grid 512 -> 2 blocks/CU (cross-block latency hiding);
//       launch_bounds(512,2) is the PROVEN cap-128/no-spill config.
//   (2) per-step inline threefry -> jump-bit LDS precompute (verified r8/r9).
// MFMA rows 8..15 compute garbage-from-zero (finite), never stored.
__global__ void __launch_bounds__(BLKT, 2) model_kernel(
    const __bf16* __restrict__ ws,
    const float* __restrict__ b1, const float* __restrict__ b2,
    const float* __restrict__ b3, const float* __restrict__ b4,
    const float* __restrict__ x0p, const float* __restrict__ sp,
    const float* __restrict__ dpp, float* __restrict__ out)
{
  __shared__ __bf16 xb[16 * 128];       // MLP input (bf16, swizzled); rows 8-15 zero
  __shared__ __bf16 actA[16 * 256];     // 512B/row, swizzled
  __shared__ __bf16 actB[16 * 256];
  __shared__ float  psum[8][16][16];    // layer-4 K-split partials
  __shared__ float  xVf[ROWS][DIM_D];   // fp32 V state (for f / exact outputs)
  __shared__ float  crf[ROWS][DIM_D];   // fp32 CR state
  __shared__ float  hVl[ROWS][DIM_D];
  __shared__ float  hDl[ROWS], fl[ROWS];
  __shared__ float  s_sh[DIM_D];
  __shared__ float  dp_sh;
  __shared__ uint32_t keys[NSTE - 1][2];
  __shared__ uint32_t jb[NSTE - 1][ROWS];  // jump bitmask per (step, row)

  const int tid = threadIdx.x;
  const int r0  = blockIdx.x * ROWS;
  char* xbB = (char*)xb;
  char* aAB = (char*)actA;
  char* aBB = (char*)actB;

  // ---------------- init ----------------
  if (tid < NSTE - 1) {
    uint32_t o0, o1;
    tf2x32(0u, 1234u, 0u, (uint32_t)tid, o0, o1);   // fold_in(key(1234), n)
    keys[tid][0] = o0; keys[tid][1] = o1;
  }
  if (tid < DIM_D) s_sh[tid] = sp[tid];
  if (tid == 0)    dp_sh = dpp[0];
  for (int i = tid; i < 16 * 128; i += BLKT) xb[i] = (__bf16)0.0f;
  __syncthreads();

  const int wv = tid >> 6;       // wave 0..7 -> N-tiles {2wv, 2wv+1}
  const int ln = tid & 63;
  const int lr = ln & 15;        // A-row / B-col within 16-tile
  const int g  = ln >> 4;        // 0..3
  const int lk8 = g * 8;         // k element offset within K-step

  // ---- jump-bit precompute: wave wv owns row wv, all 99 steps ----
  {
    const uint32_t F = (uint32_t)((r0 + wv) * DIM_D + (ln & 31));
    for (int n = 0; n < NSTE - 1; ++n) {
      uint32_t o0, o1;
      tf2x32(keys[n][0], keys[n][1], 0u, F, o0, o1);
      const uint32_t bits = o0 ^ o1;
      const float uf = __uint_as_float((bits >> 9) | 0x3f800000u) - 1.0f;
      const unsigned long long m = __ballot(uf < 0.05f);
      if (ln == 0) jb[n][wv] = (uint32_t)m;     // lanes 0..31 = dims 0..31
    }
  }

  for (int i = tid; i < ROWS * KIN; i += BLKT) {
    int r = i / KIN, c = i % KIN;
    float v = (c < 65) ? x0p[c] : 0.0f;     // col 65 = t = 0
    *(__bf16*)(xbB + swz256(r, c * 2)) = (__bf16)v;
    if (c < 65) out[X_OFF + (size_t)(r0 + r) * NSTE * 65 + c] = v;
  }
  for (int i = tid; i < ROWS * DIM_D; i += BLKT) {
    int r = i / DIM_D, d = i % DIM_D;
    xVf[r][d] = x0p[d];
    crf[r][d] = x0p[33 + d];
    hVl[r][d] = -logf(1.0f - x0p[d]) / s_sh[d];
    out[CTRL_OFF + (size_t)(r0 + r) * NSTE * DIM_D + (size_t)(NSTE - 1) * DIM_D + d] = 0.0f;
  }
  if (tid < ROWS) { hDl[tid] = x0p[DIM_D] / dp_sh; fl[tid] = 0.0f; }

  // ---------------- weight fragments in VGPRs (compiler-managed reloads) ----
  bf16x8 w1f[2][3], w2f[2][8], w3f[2][8], w4f[2];
#pragma unroll
  for (int t = 0; t < 2; ++t) {
    const int n1 = wv * 32 + t * 16 + lr;
#pragma unroll
    for (int ks = 0; ks < 3; ++ks)
      w1f[t][ks] = *(const bf16x8*)(ws + W1B_OFF + n1 * 96 + ks * 32 + lk8);
#pragma unroll
    for (int ks = 0; ks < 8; ++ks) {
      w2f[t][ks] = *(const bf16x8*)(ws + W2B_OFF + n1 * 256 + ks * 32 + lk8);
      w3f[t][ks] = *(const bf16x8*)(ws + W3B_OFF + n1 * 256 + ks * 32 + lk8);
    }
  }
  {
    const int t4 = wv >> 2, kc = wv & 3;
#pragma unroll
    for (int ks2 = 0; ks2 < 2; ++ks2)
      w4f[ks2] = *(const bf16x8*)(ws + W4B_OFF + (t4 * 16 + lr) * 256 + (kc * 2 + ks2) * 32 + lk8);
  }
  const float bb1_0 = b1[wv * 32 + lr], bb1_1 = b1[wv * 32 + 16 + lr];
  const float bb2_0 = b2[wv * 32 + lr], bb2_1 = b2[wv * 32 + 16 + lr];
  const float bb3_0 = b3[wv * 32 + lr], bb3_1 = b3[wv * 32 + 16 + lr];
  const float b4d = b4[tid & 31];
  __syncthreads();

  // ---------------- 99 steps ----------------
  for (int n = 0; n < NSTE - 1; ++n) {
    // ---- L1: xb(K=96) -> actA ----
    {
      f32x4 a0 = {bb1_0, bb1_0, bb1_0, bb1_0};
      f32x4 a1 = {bb1_1, bb1_1, bb1_1, bb1_1};
#pragma unroll
      for (int ks = 0; ks < 3; ++ks) {
        bf16x8 af = *(const bf16x8*)(xbB + swz256(lr, ks * 64 + g * 16));
        a0 = mfma16(af, w1f[0][ks], a0);
        a1 = mfma16(af, w1f[1][ks], a1);
      }
#pragma unroll
      for (int q = 0; q < 4; ++q) {
        int row = g * 4 + q;
        *(__bf16*)(aAB + swz512(row, (wv * 32 + lr) * 2))      = (__bf16)fmaxf(a0[q], 0.0f);
        *(__bf16*)(aAB + swz512(row, (wv * 32 + 16 + lr) * 2)) = (__bf16)fmaxf(a1[q], 0.0f);
      }
    }
    __syncthreads();
    // ---- L2: actA -> actB ----
    {
      f32x4 a0 = {bb2_0, bb2_0, bb2_0, bb2_0};
      f32x4 a1 = {bb2_1, bb2_1, bb2_1, bb2_1};
#pragma unroll
      for (int ks = 0; ks < 8; ++ks) {
        bf16x8 af = *(const bf16x8*)(aAB + swz512(lr, ks * 64 + g * 16));
        a0 = mfma16(af, w2f[0][ks], a0);
        a1 = mfma16(af, w2f[1][ks], a1);
      }
#pragma unroll
      for (int q = 0; q < 4; ++q) {
        int row = g * 4 + q;
        *(__bf16*)(aBB + swz512(row, (wv * 32 + lr) * 2))      = (__bf16)fmaxf(a0[q], 0.0f);
        *(__bf16*)(aBB + swz512(row, (wv * 32 + 16 + lr) * 2)) = (__bf16)fmaxf(a1[q], 0.0f);
      }
    }
    __syncthreads();
    // ---- L3: actB -> actA ----
    {
      f32x4 a0 = {bb3_0, bb3_0, bb3_0, bb3_0};
      f32x4 a1 = {bb3_1, bb3_1, bb3_1, bb3_1};
#pragma unroll
      for (int ks = 0; ks < 8; ++ks) {
        bf16x8 af = *(const bf16x8*)(aBB + swz512(lr, ks * 64 + g * 16));
        a0 = mfma16(af, w3f[0][ks], a0);
        a1 = mfma16(af, w3f[1][ks], a1);
      }
#pragma unroll
      for (int q = 0; q < 4; ++q) {
        int row = g * 4 + q;
        *(__bf16*)(aAB + swz512(row, (wv * 32 + lr) * 2))      = (__bf16)fmaxf(a0[q], 0.0f);
        *(__bf16*)(aAB + swz512(row, (wv * 32 + 16 + lr) * 2)) = (__bf16)fmaxf(a1[q], 0.0f);
      }
    }
    __syncthreads();
    // ---- L4: actA -> psum (K split: wv>>2 = tile, wv&3 = K-chunk) ----
    {
      const int kc = wv & 3;
      f32x4 a4 = {0.0f, 0.0f, 0.0f, 0.0f};
#pragma unroll
      for (int ks2 = 0; ks2 < 2; ++ks2) {
        const int ks = kc * 2 + ks2;
        bf16x8 af = *(const bf16x8*)(aAB + swz512(lr, ks * 64 + g * 16));
        a4 = mfma16(af, w4f[ks2], a4);
      }
#pragma unroll
      for (int q = 0; q < 4; ++q) psum[wv][g * 4 + q][lr] = a4[q];
    }
    if (tid < ROWS) {            // f += sum(V_old) * DT (pre-update x)
      float sum = 0.0f;
#pragma unroll
      for (int d = 0; d < DIM_D; ++d) sum += xVf[tid][d];
      fl[tid] += sum * DT_C;
    }
    __syncthreads();
    // ---- epilogue: u = sigmoid(b4 + sum psum), jump bits, state update ----
    if (tid < 256) {
      const int r = tid >> 5, d = tid & 31;
      float up = b4d;
      const int g0 = (d >> 4) * 4, c = d & 15;
#pragma unroll
      for (int w2 = 0; w2 < 4; ++w2) up += psum[g0 + w2][r][c];
      const float u = 1.0f / (1.0f + expf(-up));
      out[CTRL_OFF + (size_t)(r0 + r) * NSTE * DIM_D + (size_t)n * DIM_D + d] = u;

      const bool jump = (jb[n][r] >> d) & 1;
      float hv = jump ? 0.0f : (hVl[r][d] + DT_C);
      hVl[r][d] = hv;
      float cr = crf[r][d] + (jump ? u : 0.0f);
      crf[r][d] = cr;
      float V = 1.0f - expf(-s_sh[d] * hv);
      xVf[r][d] = V;

      const size_t xo = X_OFF + (size_t)(r0 + r) * NSTE * 65 + (size_t)(n + 1) * 65;
      out[xo + d] = V;
      out[xo + 33 + d] = cr;
      *(__bf16*)(xbB + swz256(r, d * 2))        = (__bf16)V;
      *(__bf16*)(xbB + swz256(r, (33 + d) * 2)) = (__bf16)cr;
      if (d == 0) {
        float hd = hDl[r] + DT_C; hDl[r] = hd;
        float Dv = dp_sh * hd;
        out[xo + 32] = Dv;
        *(__bf16*)(xbB + swz256(r, 64))  = (__bf16)Dv;                      // col 32
        *(__bf16*)(xbB + swz256(r, 130)) = (__bf16)(DT_C * (float)(n + 1)); // col 65 = t
      }
    }
    __syncthreads();
  }

  // ---- J = f + sum(CR_last) ----
  if (tid < ROWS) {
    float s = 0.0f;
#pragma unroll
    for (int d = 0; d < DIM_D; ++d) s += crf[tid][d];
    out[J_OFF + (size_t)(r0 + tid)] = fl[tid] + s;
  }
}

extern "C" void kernel_launch(void* const* d_in, const int* in_sizes, int n_in,
                              void* d_out, int out_size, void* d_ws, size_t ws_size,
                              hipStream_t stream) {
  const float* W1 = (const float*)d_in[0];
  const float* b1 = (const float*)d_in[1];
  const float* W2 = (const float*)d_in[2];
  const float* b2 = (const float*)d_in[3];
  const float* W3 = (const float*)d_in[4];
  const float* b3 = (const float*)d_in[5];
  const float* W4 = (const float*)d_in[6];
  const float* b4 = (const float*)d_in[7];
  const float* x0 = (const float*)d_in[8];
  const float* s  = (const float*)d_in[9];
  const float* dp = (const float*)d_in[10];
  __bf16* ws = (__bf16*)d_ws;
  float* out = (float*)d_out;

  hipLaunchKernelGGL(conv_w, dim3(WS_ELEMS / 256), dim3(256), 0, stream, W1, W2, W3, W4, ws);
  hipLaunchKernelGGL(model_kernel, dim3(NBLK), dim3(BLKT), 0, stream,
                     ws, b1, b2, b3, b4, x0, s, dp, out);
}